// Round 2
// baseline (174.807 us; speedup 1.0000x reference)
//
#include <hip/hip_runtime.h>
#include <math.h>

// Problem constants (from setup_inputs): B=16, T=8192, N=32, depth=31, 5 ops.
constexpr int N_STACK = 32;
constexpr int DEPTH = 31;
constexpr int NOPS = 5;
constexpr int BLOCK = 256;
constexpr int CH = 8;                      // steps per prefetch chunk
constexpr int NCH = (DEPTH + CH - 1) / CH; // 4 chunks: 8,8,8,7

#define LOG_LIMF 10.0f

// _clip_log(l) = tanh(l/10)*10, via tanh(x) = (e^{2x}-1)/(e^{2x}+1)
__device__ __forceinline__ float clip_log(float l) {
    float tx = 0.2f * l;                       // 2*(l/10)
    tx = fminf(fmaxf(tx, -80.0f), 80.0f);      // keep exp finite
    float t = __expf(tx);
    return 10.0f * (t - 1.0f) * __builtin_amdgcn_rcpf(t + 1.0f);
}

// add_log_space branch combine. Shared numeric pieces (l_same_c, nlog, zres, bx)
// are computed once outside (they do not depend on signs). sy is +acc for add,
// -acc for sub.
__device__ __forceinline__ void add_ls(float sx, float lx, float sy, float ly,
                                       float l_same_c, float nlog, bool zres, bool bx,
                                       float &s_o, float &l_o)
{
    bool zx = (sx == 0.0f);
    bool zy = (sy == 0.0f);
    bool both = (!zx) && (!zy);
    bool same_sign = (sx * sy > 0.0f);
    bool same_br = both && same_sign;
    bool opp_br  = both && !same_sign;

    float s = 0.0f, l = 0.0f;          // default: both zero
    if ((!zx) && zy) { s = sx; l = lx; }
    if (zx && (!zy)) { s = sy; l = ly; }
    if (same_br) { s = (sx > 0.0f) ? 1.0f : -1.0f; l = l_same_c; }
    if (opp_br)  { s = zres ? 0.0f : (bx ? sx : sy); l = nlog; }
    s_o = s;
    l_o = clip_log(l);                 // reference clips l_out on return
}

__global__ __launch_bounds__(BLOCK, 2)
void stack_fold_kernel(const float* __restrict__ sgn,
                       const float* __restrict__ logm,
                       const float* __restrict__ ops,
                       float* __restrict__ out, int n)
{
    int id = blockIdx.x * BLOCK + threadIdx.x;
    if (id >= n) return;

    // Per-thread contiguous slices; id*128 bytes => float4 aligned.
    const float4* sg4 = reinterpret_cast<const float4*>(sgn  + (size_t)id * N_STACK);
    const float4* lg4 = reinterpret_cast<const float4*>(logm + (size_t)id * N_STACK);

    float s_arr[N_STACK], l_arr[N_STACK];
#pragma unroll
    for (int i = 0; i < N_STACK / 4; ++i) {
        float4 a = sg4[i];
        float4 b = lg4[i];
        s_arr[4*i+0] = a.x; s_arr[4*i+1] = a.y; s_arr[4*i+2] = a.z; s_arr[4*i+3] = a.w;
        l_arr[4*i+0] = b.x; l_arr[4*i+1] = b.y; l_arr[4*i+2] = b.z; l_arr[4*i+3] = b.w;
    }

    const float* op = ops + (size_t)id * (DEPTH * NOPS);

    // Double-buffered register prefetch of the ops stream, CH steps per chunk.
    // Loads for chunk c+1 are issued BEFORE computing chunk c, so ~CH steps of
    // ALU work covers the (uncoalesced, ~200-900 cyc) load latency. All indices
    // are compile-time constants after unrolling -> buffers live in VGPRs.
    float buf[2][CH * NOPS];
#pragma unroll
    for (int j = 0; j < CH * NOPS; ++j) buf[0][j] = op[j];   // chunk 0 (full 40)

    // Suffix sum-of-squares of ORIGINAL logs, positions 0..30 (top excluded).
    float S = 0.0f;
#pragma unroll
    for (int i = 0; i < N_STACK - 1; ++i) S = fmaf(l_arr[i], l_arr[i], S);

    // Accumulator = top of stack.
    float as_ = s_arr[N_STACK - 1];
    float al  = l_arr[N_STACK - 1];

#pragma unroll
    for (int c = 0; c < NCH; ++c) {
        // Prefetch next chunk (guarding the 31*5=155 stream end: last chunk has 35).
        if (c + 1 < NCH) {
            float* nxt = buf[(c + 1) & 1];
            const int base = (c + 1) * CH * NOPS;
#pragma unroll
            for (int j = 0; j < CH * NOPS; ++j)
                if (base + j < DEPTH * NOPS) nxt[j] = op[base + j];
        }

        const float* cur = buf[c & 1];
#pragma unroll
        for (int j = 0; j < CH; ++j) {
            const int k = c * CH + j;
            if (k < DEPTH) {
                float ss = s_arr[N_STACK - 2 - k];   // sec (original input)
                float sl = l_arr[N_STACK - 2 - k];

                float p0 = cur[NOPS*j + 0];
                float p1 = cur[NOPS*j + 1];
                float p2 = cur[NOPS*j + 2];
                float p3 = cur[NOPS*j + 3];
                float p4 = cur[NOPS*j + 4];

                // ---- shared add/sub numeric core (sign-independent) ----
                float d = sl - al;
                float mx = fmaxf(sl, al);
                float lse = mx + __logf(1.0f + __expf(-fabsf(d)));   // logaddexp
                float l_same_c = clip_log(lse);

                bool bx = (sl >= al);                 // bigger_is_x
                float big    = bx ? sl : al;
                float small_ = bx ? al : sl;
                float delta = fminf(fmaxf(small_ - big, -LOG_LIMF), -0.001f);
                float diff = __logf(1.0f - __expf(delta));           // log1p(-exp(delta))
                bool zres = (small_ == big);
                float nlog = zres ? 0.0f : (big + diff);

                // ---- add / sub branch combines ----
                float s_add, l_add, s_sub, l_sub;
                add_ls(ss, sl,  as_, al, l_same_c, nlog, zres, bx, s_add, l_add);
                add_ls(ss, sl, -as_, al, l_same_c, nlog, zres, bx, s_sub, l_sub);

                // ---- mul / div ----
                float sm   = ss * as_;
                float lmul = clip_log(sl + al);
                float ldiv = clip_log(sl - al);

                // ---- soft mix over [add, sub, mul, div, identity(sec)] ----
                float rs = p0 * s_add + p1 * s_sub + (p2 + p3) * sm + p4 * ss;
                float rl = p0 * l_add + p1 * l_sub + p2 * lmul + p3 * ldiv + p4 * sl;

                // ---- RMS rescale: slice = original logs 0..30-k ++ rl (cs = 32-k)
                const float inv_cs = 1.0f / (float)(N_STACK - k);    // compile-time
                float ms = fmaf(rl, rl, S) * inv_cs + 1e-6f;
                float scale = fminf(10.0f * __builtin_amdgcn_rsqf(ms), 1.0f);
                rl = rl * scale;

                // retire original element 30-k from the suffix sum
                S = fmaf(-sl, sl, S);

                as_ = rs;
                al  = rl;
            }
        }
    }

    // Output: (2, B, T) flattened — [0..n) = sign, [n..2n) = log
    out[id]     = as_;
    out[n + id] = al;
}

extern "C" void kernel_launch(void* const* d_in, const int* in_sizes, int n_in,
                              void* d_out, int out_size, void* d_ws, size_t ws_size,
                              hipStream_t stream) {
    const float* sgn  = (const float*)d_in[0];
    const float* logm = (const float*)d_in[1];
    const float* ops  = (const float*)d_in[2];
    float* out = (float*)d_out;

    int n = in_sizes[0] / N_STACK;   // B*T = 131072
    int blocks = (n + BLOCK - 1) / BLOCK;
    stack_fold_kernel<<<blocks, BLOCK, 0, stream>>>(sgn, logm, ops, out, n);
}

// Round 3
// 150.962 us; speedup vs baseline: 1.1580x; 1.1580x over previous
//
#include <hip/hip_runtime.h>
#include <math.h>

// Problem constants (from setup_inputs): B=16, T=8192, N=32, depth=31, 5 ops.
constexpr int N_STACK = 32;
constexpr int DEPTH = 31;
constexpr int NOPS = 5;
constexpr int BLOCK = 256;
constexpr int CH = 8;                      // steps per prefetch chunk
constexpr int NCH = (DEPTH + CH - 1) / CH; // 4 chunks: 8,8,8,7

#define LOG_LIMF 10.0f

// Force x to be materialized in a VGPR here; the result is opaque, so the
// compiler cannot re-sink / rematerialize the producing load at the use site.
#define PIN(x) asm volatile("" : "+v"(x))

// _clip_log(l) = tanh(l/10)*10, via tanh(x) = (e^{2x}-1)/(e^{2x}+1)
__device__ __forceinline__ float clip_log(float l) {
    float tx = 0.2f * l;                       // 2*(l/10)
    tx = fminf(fmaxf(tx, -80.0f), 80.0f);      // keep exp finite
    float t = __expf(tx);
    return 10.0f * (t - 1.0f) * __builtin_amdgcn_rcpf(t + 1.0f);
}

// add_log_space branch combine. Shared numeric pieces (l_same_c, nlog, zres, bx)
// are computed once outside (they do not depend on signs). sy is +acc for add,
// -acc for sub.
__device__ __forceinline__ void add_ls(float sx, float lx, float sy, float ly,
                                       float l_same_c, float nlog, bool zres, bool bx,
                                       float &s_o, float &l_o)
{
    bool zx = (sx == 0.0f);
    bool zy = (sy == 0.0f);
    bool both = (!zx) && (!zy);
    bool same_sign = (sx * sy > 0.0f);
    bool same_br = both && same_sign;
    bool opp_br  = both && !same_sign;

    float s = 0.0f, l = 0.0f;          // default: both zero
    if ((!zx) && zy) { s = sx; l = lx; }
    if (zx && (!zy)) { s = sy; l = ly; }
    if (same_br) { s = (sx > 0.0f) ? 1.0f : -1.0f; l = l_same_c; }
    if (opp_br)  { s = zres ? 0.0f : (bx ? sx : sy); l = nlog; }
    s_o = s;
    l_o = clip_log(l);                 // reference clips l_out on return
}

// Grid is hard-capped at 2 waves/SIMD (131072 thr = 2048 waves on 1024 SIMDs),
// so tell the scheduler occupancy can't exceed 2 waves/EU: pressure target
// becomes ~256 VGPRs and loads get hoisted instead of sunk.
__global__ __launch_bounds__(BLOCK)
__attribute__((amdgpu_waves_per_eu(2, 2)))
void stack_fold_kernel(const float* __restrict__ sgn,
                       const float* __restrict__ logm,
                       const float* __restrict__ ops,
                       float* __restrict__ out, int n)
{
    int id = blockIdx.x * BLOCK + threadIdx.x;
    if (id >= n) return;

    // Per-thread contiguous slices; id*128 bytes => float4 aligned.
    const float4* sg4 = reinterpret_cast<const float4*>(sgn  + (size_t)id * N_STACK);
    const float4* lg4 = reinterpret_cast<const float4*>(logm + (size_t)id * N_STACK);
    const float* op = ops + (size_t)id * (DEPTH * NOPS);

    // ---- issue ALL stack loads + chunk-0 ops loads, then pin ----
    float s_arr[N_STACK], l_arr[N_STACK];
#pragma unroll
    for (int i = 0; i < N_STACK / 4; ++i) {
        float4 a = sg4[i];
        float4 b = lg4[i];
        s_arr[4*i+0] = a.x; s_arr[4*i+1] = a.y; s_arr[4*i+2] = a.z; s_arr[4*i+3] = a.w;
        l_arr[4*i+0] = b.x; l_arr[4*i+1] = b.y; l_arr[4*i+2] = b.z; l_arr[4*i+3] = b.w;
    }

    float cur[CH * NOPS];
#pragma unroll
    for (int j = 0; j < CH * NOPS; ++j) cur[j] = op[j];   // chunk 0 (full 40)

    // Pin the 64 stack values + 40 chunk-0 probs into live VGPRs.
#pragma unroll
    for (int i = 0; i < N_STACK; ++i) { PIN(s_arr[i]); PIN(l_arr[i]); }
#pragma unroll
    for (int j = 0; j < CH * NOPS; ++j) PIN(cur[j]);

    // Suffix sum-of-squares of ORIGINAL logs, positions 0..30 (top excluded).
    float S = 0.0f;
#pragma unroll
    for (int i = 0; i < N_STACK - 1; ++i) S = fmaf(l_arr[i], l_arr[i], S);

    // Accumulator = top of stack.
    float as_ = s_arr[N_STACK - 1];
    float al  = l_arr[N_STACK - 1];

#pragma unroll
    for (int c = 0; c < NCH; ++c) {
        // Issue loads for chunk c+1 NOW (they complete under chunk-c compute).
        float nxt[CH * NOPS];
        if (c + 1 < NCH) {
            const int base = (c + 1) * CH * NOPS;
#pragma unroll
            for (int j = 0; j < CH * NOPS; ++j)
                nxt[j] = (base + j < DEPTH * NOPS) ? op[base + j] : 0.0f;
        }

#pragma unroll
        for (int j = 0; j < CH; ++j) {
            const int k = c * CH + j;
            if (k < DEPTH) {
                float ss = s_arr[N_STACK - 2 - k];   // sec (original input)
                float sl = l_arr[N_STACK - 2 - k];

                float p0 = cur[NOPS*j + 0];
                float p1 = cur[NOPS*j + 1];
                float p2 = cur[NOPS*j + 2];
                float p3 = cur[NOPS*j + 3];
                float p4 = cur[NOPS*j + 4];

                // ---- shared add/sub numeric core (sign-independent) ----
                float d = sl - al;
                float mx = fmaxf(sl, al);
                float lse = mx + __logf(1.0f + __expf(-fabsf(d)));   // logaddexp
                float l_same_c = clip_log(lse);

                bool bx = (sl >= al);                 // bigger_is_x
                float big    = bx ? sl : al;
                float small_ = bx ? al : sl;
                float delta = fminf(fmaxf(small_ - big, -LOG_LIMF), -0.001f);
                float diff = __logf(1.0f - __expf(delta));           // log1p(-exp(delta))
                bool zres = (small_ == big);
                float nlog = zres ? 0.0f : (big + diff);

                // ---- add / sub branch combines ----
                float s_add, l_add, s_sub, l_sub;
                add_ls(ss, sl,  as_, al, l_same_c, nlog, zres, bx, s_add, l_add);
                add_ls(ss, sl, -as_, al, l_same_c, nlog, zres, bx, s_sub, l_sub);

                // ---- mul / div ----
                float sm   = ss * as_;
                float lmul = clip_log(sl + al);
                float ldiv = clip_log(sl - al);

                // ---- soft mix over [add, sub, mul, div, identity(sec)] ----
                float rs = p0 * s_add + p1 * s_sub + (p2 + p3) * sm + p4 * ss;
                float rl = p0 * l_add + p1 * l_sub + p2 * lmul + p3 * ldiv + p4 * sl;

                // ---- RMS rescale: slice = original logs 0..30-k ++ rl (cs = 32-k)
                const float inv_cs = 1.0f / (float)(N_STACK - k);    // compile-time
                float ms = fmaf(rl, rl, S) * inv_cs + 1e-6f;
                float scale = fminf(10.0f * __builtin_amdgcn_rsqf(ms), 1.0f);
                rl = rl * scale;

                // retire original element 30-k from the suffix sum
                S = fmaf(-sl, sl, S);

                as_ = rs;
                al  = rl;
            }
        }

        // Pin chunk c+1 AFTER chunk-c compute: the waitcnt lands here, behind
        // ~8 steps (~1000 cyc) of ALU work, then roll buffers (free renaming).
        if (c + 1 < NCH) {
#pragma unroll
            for (int j = 0; j < CH * NOPS; ++j) { PIN(nxt[j]); cur[j] = nxt[j]; }
        }
    }

    // Output: (2, B, T) flattened — [0..n) = sign, [n..2n) = log
    out[id]     = as_;
    out[n + id] = al;
}

extern "C" void kernel_launch(void* const* d_in, const int* in_sizes, int n_in,
                              void* d_out, int out_size, void* d_ws, size_t ws_size,
                              hipStream_t stream) {
    const float* sgn  = (const float*)d_in[0];
    const float* logm = (const float*)d_in[1];
    const float* ops  = (const float*)d_in[2];
    float* out = (float*)d_out;

    int n = in_sizes[0] / N_STACK;   // B*T = 131072
    int blocks = (n + BLOCK - 1) / BLOCK;
    stack_fold_kernel<<<blocks, BLOCK, 0, stream>>>(sgn, logm, ops, out, n);
}